// Round 1
// baseline (3302.645 us; speedup 1.0000x reference)
//
#include <hip/hip_runtime.h>
#include <hip/hip_bf16.h>

// Problem constants (match reference)
constexpr int B = 8192;
constexpr int G = 1024;
constexpr int E = 256;
constexpr int K = 2048;
constexpr float P_NULL = 0.1f;
constexpr int N_STEP = 4;

// ---------------------------------------------------------------------------
// Reduction helpers (256-thread blocks, wave64)
// ---------------------------------------------------------------------------
__device__ inline float wave_sum(float v) {
#pragma unroll
    for (int off = 32; off > 0; off >>= 1) v += __shfl_down(v, off, 64);
    return v;
}
__device__ inline float wave_max(float v) {
#pragma unroll
    for (int off = 32; off > 0; off >>= 1) v = fmaxf(v, __shfl_down(v, off, 64));
    return v;
}
__device__ inline float block_sum256(float v, float* sm) {
    v = wave_sum(v);
    const int w = threadIdx.x >> 6;
    if ((threadIdx.x & 63) == 0) sm[w] = v;
    __syncthreads();
    const float r = sm[0] + sm[1] + sm[2] + sm[3];
    __syncthreads();
    return r;
}
__device__ inline float block_max256(float v, float* sm) {
    v = wave_max(v);
    const int w = threadIdx.x >> 6;
    if ((threadIdx.x & 63) == 0) sm[w] = v;
    __syncthreads();
    const float r = fmaxf(fmaxf(sm[0], sm[1]), fmaxf(sm[2], sm[3]));
    __syncthreads();
    return r;
}

// ---------------------------------------------------------------------------
// Column mean-of-squares: out[k] += (1/rows) * sum_r M[r,k]^2  (atomic partial)
// grid: (cols/256, ceil(rows/128)), block 256. out must be pre-zeroed.
// ---------------------------------------------------------------------------
__global__ __launch_bounds__(256) void colsq_kernel(
    const float* __restrict__ M, int rows, int cols, float inv_rows,
    float* __restrict__ out) {
    const int k = blockIdx.x * 256 + threadIdx.x;
    const int r0 = blockIdx.y * 128;
    const int r1 = min(r0 + 128, rows);
    float s = 0.f;
    for (int r = r0; r < r1; ++r) {
        const float v = M[(size_t)r * cols + k];
        s = fmaf(v, v, s);
    }
    atomicAdd(out + k, s * inv_rows);
}

// ---------------------------------------------------------------------------
// Tiled f32 GEMM, 64x64 tile, BK=32, 256 threads, 4x4 per thread.
// BT=false: C[m,n] = alpha * sum_c A[m,c]*Bm[c,n] - bias[n]   (Bm is (Kd,N))
// BT=true : C[m,n] = alpha * sum_c A[m,c]*Bm[n,c] - bias[n]   (Bm is (N,Kd))
// M,N divisible by 64; Kd divisible by 32. bias may be null.
// ---------------------------------------------------------------------------
template <bool BT>
__global__ __launch_bounds__(256) void gemm64_kernel(
    const float* __restrict__ A, const float* __restrict__ Bm,
    float* __restrict__ C, int M, int N, int Kd, float alpha,
    const float* __restrict__ bias) {
    __shared__ float As[64 * 33];
    __shared__ float Bs[32 * 65];
    const int tid = threadIdx.x;
    const int tx = tid & 15, ty = tid >> 4;
    const int row0 = blockIdx.y * 64, col0 = blockIdx.x * 64;
    float acc[4][4] = {};

    for (int k0 = 0; k0 < Kd; k0 += 32) {
#pragma unroll
        for (int l = 0; l < 8; ++l) {
            const int idx = tid + l * 256;
            const int r = idx >> 5, c = idx & 31;
            As[r * 33 + c] = A[(size_t)(row0 + r) * Kd + k0 + c];
        }
#pragma unroll
        for (int l = 0; l < 8; ++l) {
            const int idx = tid + l * 256;
            if (BT) {
                const int n = idx >> 5, c = idx & 31;
                Bs[c * 65 + n] = Bm[(size_t)(col0 + n) * Kd + k0 + c];
            } else {
                const int c = idx >> 6, n = idx & 63;
                Bs[c * 65 + n] = Bm[(size_t)(k0 + c) * N + col0 + n];
            }
        }
        __syncthreads();
#pragma unroll
        for (int kk = 0; kk < 32; ++kk) {
            float a[4], b[4];
#pragma unroll
            for (int i = 0; i < 4; ++i) a[i] = As[(ty * 4 + i) * 33 + kk];
#pragma unroll
            for (int j = 0; j < 4; ++j) b[j] = Bs[kk * 65 + tx * 4 + j];
#pragma unroll
            for (int i = 0; i < 4; ++i)
#pragma unroll
                for (int j = 0; j < 4; ++j)
                    acc[i][j] = fmaf(a[i], b[j], acc[i][j]);
        }
        __syncthreads();
    }

#pragma unroll
    for (int i = 0; i < 4; ++i) {
        const int r = row0 + ty * 4 + i;
#pragma unroll
        for (int j = 0; j < 4; ++j) {
            const int c = col0 + tx * 4 + j;
            float v = alpha * acc[i][j];
            if (bias) v -= bias[c];
            C[(size_t)r * N + c] = v;
        }
    }
}

// ---------------------------------------------------------------------------
// GEMM4 + loss: recon = A @ Bm^T (A: (B,K) xq-normed, Bm: (G,K) = xa),
// then loss[b] += (1/G) * sum_g (recon[b,g] - X[b,g])^2  (atomic per g-tile)
// ---------------------------------------------------------------------------
__global__ __launch_bounds__(256) void gemm_loss_kernel(
    const float* __restrict__ A, const float* __restrict__ Bm,
    const float* __restrict__ X, float* __restrict__ loss,
    int M, int N, int Kd) {
    __shared__ float As[64 * 33];
    __shared__ float Bs[32 * 65];
    __shared__ float red[64 * 17];
    const int tid = threadIdx.x;
    const int tx = tid & 15, ty = tid >> 4;
    const int row0 = blockIdx.y * 64, col0 = blockIdx.x * 64;
    float acc[4][4] = {};

    for (int k0 = 0; k0 < Kd; k0 += 32) {
#pragma unroll
        for (int l = 0; l < 8; ++l) {
            const int idx = tid + l * 256;
            const int r = idx >> 5, c = idx & 31;
            As[r * 33 + c] = A[(size_t)(row0 + r) * Kd + k0 + c];
        }
#pragma unroll
        for (int l = 0; l < 8; ++l) {
            const int idx = tid + l * 256;
            const int n = idx >> 5, c = idx & 31;
            Bs[c * 65 + n] = Bm[(size_t)(col0 + n) * Kd + k0 + c];
        }
        __syncthreads();
#pragma unroll
        for (int kk = 0; kk < 32; ++kk) {
            float a[4], b[4];
#pragma unroll
            for (int i = 0; i < 4; ++i) a[i] = As[(ty * 4 + i) * 33 + kk];
#pragma unroll
            for (int j = 0; j < 4; ++j) b[j] = Bs[kk * 65 + tx * 4 + j];
#pragma unroll
            for (int i = 0; i < 4; ++i)
#pragma unroll
                for (int j = 0; j < 4; ++j)
                    acc[i][j] = fmaf(a[i], b[j], acc[i][j]);
        }
        __syncthreads();
    }

    // epilogue: squared error vs X, partial-reduce over the 64-col tile
    float psum[4];
#pragma unroll
    for (int i = 0; i < 4; ++i) {
        const int r = row0 + ty * 4 + i;
        float s = 0.f;
#pragma unroll
        for (int j = 0; j < 4; ++j) {
            const int c = col0 + tx * 4 + j;
            const float d = acc[i][j] - X[(size_t)r * N + c];
            s = fmaf(d, d, s);
        }
        psum[i] = s;
    }
#pragma unroll
    for (int i = 0; i < 4; ++i) red[(ty * 4 + i) * 17 + tx] = psum[i];
    __syncthreads();
    if (tid < 64) {
        float s = 0.f;
        for (int t2 = 0; t2 < 16; ++t2) s += red[tid * 17 + t2];
        atomicAdd(&loss[row0 + tid], s * (1.0f / (float)N));
    }
}

// ---------------------------------------------------------------------------
// Row softmax over K=2048: P[row,:] = softmax(L[row,:]). One block per row.
// ---------------------------------------------------------------------------
__global__ __launch_bounds__(256) void softmax_kernel(
    const float* __restrict__ L, float* __restrict__ P) {
    __shared__ float sm[4];
    const size_t base = (size_t)blockIdx.x * K;
    float v[8];
    float m = -1e30f;
#pragma unroll
    for (int i = 0; i < 8; ++i) {
        v[i] = L[base + threadIdx.x + i * 256];
        m = fmaxf(m, v[i]);
    }
    m = block_max256(m, sm);
    float s = 0.f;
#pragma unroll
    for (int i = 0; i < 8; ++i) {
        v[i] = __expf(v[i] - m);
        s += v[i];
    }
    s = block_sum256(s, sm);
    const float inv = 1.f / s;
#pragma unroll
    for (int i = 0; i < 8; ++i) P[base + threadIdx.x + i * 256] = v[i] * inv;
}

// ---------------------------------------------------------------------------
// Loop reweight (in place on T): T = pik*exp(T - rowmax); T /= rowsum(T)
// (P_NULL and per-row x2 cancel in this normalization — see analysis.)
// ---------------------------------------------------------------------------
__global__ __launch_bounds__(256) void reweight_kernel(
    float* __restrict__ T, const float* __restrict__ P) {
    __shared__ float sm[4];
    const size_t base = (size_t)blockIdx.x * K;
    float v[8];
    float m = -1e30f;
#pragma unroll
    for (int i = 0; i < 8; ++i) {
        v[i] = T[base + threadIdx.x + i * 256];
        m = fmaxf(m, v[i]);
    }
    m = block_max256(m, sm);
    float s = 0.f;
#pragma unroll
    for (int i = 0; i < 8; ++i) {
        v[i] = P[base + threadIdx.x + i * 256] * __expf(v[i] - m);
        s += v[i];
    }
    s = block_sum256(s, sm);
    const float inv = 1.f / s;
#pragma unroll
    for (int i = 0; i < 8; ++i) T[base + threadIdx.x + i * 256] = v[i] * inv;
}

// ---------------------------------------------------------------------------
// Row mean of squares of Z (B,E): x2[row] = mean(Z[row,:]^2). Block=256=E.
// ---------------------------------------------------------------------------
__global__ __launch_bounds__(256) void rowmeansq_kernel(
    const float* __restrict__ Z, float* __restrict__ out) {
    __shared__ float sm[4];
    const float v = Z[(size_t)blockIdx.x * E + threadIdx.x];
    const float s = block_sum256(v * v, sm);
    if (threadIdx.x == 0) out[blockIdx.x] = s * (1.0f / (float)E);
}

// ---------------------------------------------------------------------------
// Decode normalize (in place on T): xq = exp(T - x2[row]);
// T = xq / (P_NULL + rowsum(xq))
// ---------------------------------------------------------------------------
__global__ __launch_bounds__(256) void decode_kernel(
    float* __restrict__ T, const float* __restrict__ x2z) {
    __shared__ float sm[4];
    const size_t base = (size_t)blockIdx.x * K;
    const float x2 = x2z[blockIdx.x];
    float v[8];
    float s = 0.f;
#pragma unroll
    for (int i = 0; i < 8; ++i) {
        v[i] = __expf(T[base + threadIdx.x + i * 256] - x2);
        s += v[i];
    }
    s = block_sum256(s, sm);
    const float scale = 1.f / (P_NULL + s);
#pragma unroll
    for (int i = 0; i < 8; ++i) T[base + threadIdx.x + i * 256] = v[i] * scale;
}

// ---------------------------------------------------------------------------
extern "C" void kernel_launch(void* const* d_in, const int* in_sizes, int n_in,
                              void* d_out, int out_size, void* d_ws, size_t ws_size,
                              hipStream_t stream) {
    const float* images = (const float*)d_in[0];  // (B,G)
    const float* xa     = (const float*)d_in[1];  // (G,K)
    const float* xb     = (const float*)d_in[2];  // (E,K)
    float* out = (float*)d_out;                   // (B,)

    // workspace layout (floats): pik[B*K] | tbuf[B*K] | z[B*E] | x2z[B] | c2a[K] | c2b[K]
    float* pik  = (float*)d_ws;
    float* tbuf = pik + (size_t)B * K;
    float* z    = tbuf + (size_t)B * K;
    float* x2z  = z + (size_t)B * E;
    float* c2a  = x2z + B;
    float* c2b  = c2a + K;

    // zero the accumulated buffers (harness poisons d_out/d_ws with 0xAA)
    hipMemsetAsync(d_out, 0, (size_t)B * sizeof(float), stream);
    hipMemsetAsync(c2a, 0, (size_t)2 * K * sizeof(float), stream);

    // c2a[k] = mean_g xa[g,k]^2 ; c2b[k] = mean_e xb[e,k]^2
    colsq_kernel<<<dim3(K / 256, G / 128), 256, 0, stream>>>(xa, G, K, 1.0f / G, c2a);
    colsq_kernel<<<dim3(K / 256, E / 128), 256, 0, stream>>>(xb, E, K, 1.0f / E, c2b);

    // encode: lpik' = images@xa * (2/G) - c2a  (per-row x2 cancels in softmax)
    gemm64_kernel<false><<<dim3(K / 64, B / 64), 256, 0, stream>>>(
        images, xa, tbuf, B, K, G, 2.0f / (float)G, c2a);
    softmax_kernel<<<B, 256, 0, stream>>>(tbuf, pik);

    // z = pik @ xb^T
    gemm64_kernel<true><<<dim3(E / 64, B / 64), 256, 0, stream>>>(
        pik, xb, z, B, E, K, 1.0f, nullptr);

    for (int s = 0; s < N_STEP; ++s) {
        // t = z@xb * (2/E) - c2b
        gemm64_kernel<false><<<dim3(K / 64, B / 64), 256, 0, stream>>>(
            z, xb, tbuf, B, K, E, 2.0f / (float)E, c2b);
        // xp = pik*exp(t - max) / sum  (in place in tbuf)
        reweight_kernel<<<B, 256, 0, stream>>>(tbuf, pik);
        // z = xp @ xb^T
        gemm64_kernel<true><<<dim3(E / 64, B / 64), 256, 0, stream>>>(
            tbuf, xb, z, B, E, K, 1.0f, nullptr);
    }

    // decode
    rowmeansq_kernel<<<B, 256, 0, stream>>>(z, x2z);
    gemm64_kernel<false><<<dim3(K / 64, B / 64), 256, 0, stream>>>(
        z, xb, tbuf, B, K, E, 2.0f / (float)E, c2b);
    decode_kernel<<<B, 256, 0, stream>>>(tbuf, x2z);

    // recon = xqn @ xa^T ; loss[b] = mean_g (recon - images)^2
    gemm_loss_kernel<<<dim3(G / 64, B / 64), 256, 0, stream>>>(
        tbuf, xa, images, out, B, G, K);
}

// Round 3
// 676.315 us; speedup vs baseline: 4.8833x; 4.8833x over previous
//
#include <hip/hip_runtime.h>
#include <hip/hip_bf16.h>

// Problem constants (match reference)
constexpr int B = 8192;
constexpr int G = 1024;
constexpr int E = 256;
constexpr int K = 2048;
constexpr float P_NULL = 0.1f;
constexpr int N_STEP = 4;

typedef unsigned short u16;
typedef short bf16x8 __attribute__((ext_vector_type(8)));
typedef float f32x4 __attribute__((ext_vector_type(4)));

// ---------------------------------------------------------------------------
// bf16 <-> f32 (RNE, matches np/jax bfloat16 cast for finite values)
// ---------------------------------------------------------------------------
__device__ inline u16 f2bf(float f) {
    union { float f; uint32_t u; } cv;
    cv.f = f;
    const uint32_t u = cv.u;
    return (u16)((u + 0x7fffu + ((u >> 16) & 1u)) >> 16);
}
__device__ inline float bf2f(u16 h) {
    union { uint32_t u; float f; } cv;
    cv.u = ((uint32_t)h) << 16;
    return cv.f;
}
__device__ inline void unpack8(uint4 u, float* v) {
    v[0] = bf2f((u16)(u.x & 0xffff)); v[1] = bf2f((u16)(u.x >> 16));
    v[2] = bf2f((u16)(u.y & 0xffff)); v[3] = bf2f((u16)(u.y >> 16));
    v[4] = bf2f((u16)(u.z & 0xffff)); v[5] = bf2f((u16)(u.z >> 16));
    v[6] = bf2f((u16)(u.w & 0xffff)); v[7] = bf2f((u16)(u.w >> 16));
}
__device__ inline uint4 pack8(const float* v) {
    uint4 u;
    u.x = (uint32_t)f2bf(v[0]) | ((uint32_t)f2bf(v[1]) << 16);
    u.y = (uint32_t)f2bf(v[2]) | ((uint32_t)f2bf(v[3]) << 16);
    u.z = (uint32_t)f2bf(v[4]) | ((uint32_t)f2bf(v[5]) << 16);
    u.w = (uint32_t)f2bf(v[6]) | ((uint32_t)f2bf(v[7]) << 16);
    return u;
}

// async global->LDS, 16B per lane (lds dest must be uniform base + lane*16)
typedef __attribute__((address_space(1))) const void* gaddr_t;
typedef __attribute__((address_space(3))) void* laddr_t;
__device__ inline void gload_lds16(const void* g, void* l) {
    __builtin_amdgcn_global_load_lds((gaddr_t)g, (laddr_t)l, 16, 0, 0);
}

// ---------------------------------------------------------------------------
// Reduction helpers (256-thread blocks, wave64)
// ---------------------------------------------------------------------------
__device__ inline float wave_sum(float v) {
#pragma unroll
    for (int off = 32; off > 0; off >>= 1) v += __shfl_down(v, off, 64);
    return v;
}
__device__ inline float wave_max(float v) {
#pragma unroll
    for (int off = 32; off > 0; off >>= 1) v = fmaxf(v, __shfl_down(v, off, 64));
    return v;
}
__device__ inline float block_sum256(float v, float* sm) {
    v = wave_sum(v);
    const int w = threadIdx.x >> 6;
    if ((threadIdx.x & 63) == 0) sm[w] = v;
    __syncthreads();
    const float r = sm[0] + sm[1] + sm[2] + sm[3];
    __syncthreads();
    return r;
}
__device__ inline float block_max256(float v, float* sm) {
    v = wave_max(v);
    const int w = threadIdx.x >> 6;
    if ((threadIdx.x & 63) == 0) sm[w] = v;
    __syncthreads();
    const float r = fmaxf(fmaxf(sm[0], sm[1]), fmaxf(sm[2], sm[3]));
    __syncthreads();
    return r;
}

// ---------------------------------------------------------------------------
// f32 -> bf16 flat convert, 8 elems/thread
// ---------------------------------------------------------------------------
__global__ __launch_bounds__(256) void f2bf_kernel(
    const float* __restrict__ in, u16* __restrict__ out, int n) {
    const int i = (blockIdx.x * 256 + threadIdx.x) * 8;
    if (i + 7 >= n) {
        for (int j = i; j < n; ++j) out[j] = f2bf(in[j]);
        return;
    }
    const float4 a = *(const float4*)(in + i);
    const float4 b = *(const float4*)(in + i + 4);
    float v[8] = {a.x, a.y, a.z, a.w, b.x, b.y, b.z, b.w};
    *(uint4*)(out + i) = pack8(v);
}

// ---------------------------------------------------------------------------
// f32 (R,C) -> bf16 (C,R) transpose. grid (C/32, R/32), block 256.
// ---------------------------------------------------------------------------
__global__ __launch_bounds__(256) void transpose_bf_kernel(
    const float* __restrict__ in, u16* __restrict__ out, int R, int C) {
    __shared__ float tile[32][33];
    const int bx = blockIdx.x * 32, by = blockIdx.y * 32;
    const int x = threadIdx.x & 31, y0 = threadIdx.x >> 5;
#pragma unroll
    for (int yy = 0; yy < 32; yy += 8)
        tile[y0 + yy][x] = in[(size_t)(by + y0 + yy) * C + bx + x];
    __syncthreads();
#pragma unroll
    for (int yy = 0; yy < 32; yy += 8)
        out[(size_t)(bx + y0 + yy) * R + by + x] = f2bf(tile[x][y0 + yy]);
}

// ---------------------------------------------------------------------------
// Column mean-of-squares (f32 in): out[k] += inv_rows * sum_r M[r,k]^2
// ---------------------------------------------------------------------------
__global__ __launch_bounds__(256) void colsq_kernel(
    const float* __restrict__ M, int rows, int cols, float inv_rows,
    float* __restrict__ out) {
    const int k = blockIdx.x * 256 + threadIdx.x;
    const int r0 = blockIdx.y * 128;
    const int r1 = min(r0 + 128, rows);
    float s = 0.f;
    for (int r = r0; r < r1; ++r) {
        const float v = M[(size_t)r * cols + k];
        s = fmaf(v, v, s);
    }
    atomicAdd(out + k, s * inv_rows);
}

// ---------------------------------------------------------------------------
// MFMA bf16 GEMM: C = A(M,Kd) x Bm(N,Kd)^T  (Bm in B^T layout)
// 128x128 tile, BK=64, 256 threads = 4 waves, each wave 64x64 via 4x4 MFMAs.
// Epilogues:
//   EPI_BIAS_BF16: out bf16 = alpha*acc - bias[col]
//   EPI_BF16:      out bf16 = acc
//   EPI_LOSS:      loss[row] += (1/N) * sum_col (acc - X[row,col])^2
// M,N % 128 == 0, Kd % 64 == 0.
// ---------------------------------------------------------------------------
enum { EPI_BIAS_BF16 = 0, EPI_BF16 = 1, EPI_LOSS = 2 };

template <int EPI>
__global__ __launch_bounds__(256) void mfma_gemm_kernel(
    const u16* __restrict__ A, const u16* __restrict__ Bm,
    void* __restrict__ Cout, const float* __restrict__ bias,
    const float* __restrict__ X, int M, int N, int Kd, float alpha) {
    __shared__ u16 As[128 * 64];
    __shared__ u16 Bs[128 * 64];
    const int tid = threadIdx.x;
    const int row0 = blockIdx.y * 128, col0 = blockIdx.x * 128;
    const int lane = tid & 63, wave = tid >> 6;
    const int wr = (wave >> 1) * 64, wc = (wave & 1) * 64;
    const int tx = lane & 15, quad = lane >> 4;

    f32x4 acc[4][4] = {};

    for (int k0 = 0; k0 < Kd; k0 += 64) {
        // stage A-tile (128 rows x 64 cols bf16 = 16 KB), 4 issues x 256 lanes x 16B
#pragma unroll
        for (int l = 0; l < 4; ++l) {
            const int lin = l * 2048 + tid * 8;            // element index in tile
            const int r = lin >> 6, c = lin & 63;
            gload_lds16(A + (size_t)(row0 + r) * Kd + k0 + c, &As[lin]);
        }
#pragma unroll
        for (int l = 0; l < 4; ++l) {
            const int lin = l * 2048 + tid * 8;
            const int r = lin >> 6, c = lin & 63;
            gload_lds16(Bm + (size_t)(col0 + r) * Kd + k0 + c, &Bs[lin]);
        }
        __syncthreads();
#pragma unroll
        for (int ks = 0; ks < 2; ++ks) {
            bf16x8 af[4], bfr[4];
#pragma unroll
            for (int i = 0; i < 4; ++i)
                af[i] = *(const bf16x8*)&As[(wr + i * 16 + tx) * 64 + ks * 32 + quad * 8];
#pragma unroll
            for (int j = 0; j < 4; ++j)
                bfr[j] = *(const bf16x8*)&Bs[(wc + j * 16 + tx) * 64 + ks * 32 + quad * 8];
#pragma unroll
            for (int i = 0; i < 4; ++i)
#pragma unroll
                for (int j = 0; j < 4; ++j)
                    acc[i][j] = __builtin_amdgcn_mfma_f32_16x16x32_bf16(
                        af[i], bfr[j], acc[i][j], 0, 0, 0);
        }
        __syncthreads();
    }

    // C/D layout (m89-verified): col = lane&15, row = (lane>>4)*4 + reg
    if (EPI == EPI_LOSS) {
        float* loss = (float*)Cout;
        const float inv_n = 1.0f / (float)N;
#pragma unroll
        for (int i = 0; i < 4; ++i) {
#pragma unroll
            for (int r = 0; r < 4; ++r) {
                const int row = row0 + wr + i * 16 + quad * 4 + r;
                float s = 0.f;
#pragma unroll
                for (int j = 0; j < 4; ++j) {
                    const int col = col0 + wc + j * 16 + tx;
                    const float d = acc[i][j][r] - X[(size_t)row * N + col];
                    s = fmaf(d, d, s);
                }
                s += __shfl_xor(s, 1, 64);
                s += __shfl_xor(s, 2, 64);
                s += __shfl_xor(s, 4, 64);
                s += __shfl_xor(s, 8, 64);
                if (tx == 0) atomicAdd(&loss[row], s * inv_n);
            }
        }
    } else {
        u16* C = (u16*)Cout;
#pragma unroll
        for (int i = 0; i < 4; ++i)
#pragma unroll
            for (int j = 0; j < 4; ++j)
#pragma unroll
                for (int r = 0; r < 4; ++r) {
                    const int row = row0 + wr + i * 16 + quad * 4 + r;
                    const int col = col0 + wc + j * 16 + tx;
                    float v = acc[i][j][r];
                    if (EPI == EPI_BIAS_BF16) v = fmaf(v, alpha, -bias[col]);
                    C[(size_t)row * N + col] = f2bf(v);
                }
    }
}

// ---------------------------------------------------------------------------
// Row softmax over K=2048 (bf16 in/out). One block (256 thr) per row.
// ---------------------------------------------------------------------------
__global__ __launch_bounds__(256) void softmax_bf_kernel(
    const u16* __restrict__ T, u16* __restrict__ P) {
    __shared__ float sm[4];
    const size_t base = (size_t)blockIdx.x * K + (size_t)threadIdx.x * 8;
    float v[8];
    unpack8(*(const uint4*)(T + base), v);
    float m = v[0];
#pragma unroll
    for (int i = 1; i < 8; ++i) m = fmaxf(m, v[i]);
    m = block_max256(m, sm);
    float s = 0.f;
#pragma unroll
    for (int i = 0; i < 8; ++i) {
        v[i] = __expf(v[i] - m);
        s += v[i];
    }
    s = block_sum256(s, sm);
    const float inv = 1.f / s;
#pragma unroll
    for (int i = 0; i < 8; ++i) v[i] *= inv;
    *(uint4*)(P + base) = pack8(v);
}

// ---------------------------------------------------------------------------
// Loop reweight: XP = pik*exp(t - rowmax); XP /= rowsum  (bf16 in/out)
// (P_NULL and per-row x2 cancel in this normalization.)
// ---------------------------------------------------------------------------
__global__ __launch_bounds__(256) void reweight_bf_kernel(
    const u16* __restrict__ T, const u16* __restrict__ P,
    u16* __restrict__ XP) {
    __shared__ float sm[4];
    const size_t base = (size_t)blockIdx.x * K + (size_t)threadIdx.x * 8;
    float v[8], p[8];
    unpack8(*(const uint4*)(T + base), v);
    unpack8(*(const uint4*)(P + base), p);
    float m = v[0];
#pragma unroll
    for (int i = 1; i < 8; ++i) m = fmaxf(m, v[i]);
    m = block_max256(m, sm);
    float s = 0.f;
#pragma unroll
    for (int i = 0; i < 8; ++i) {
        v[i] = p[i] * __expf(v[i] - m);
        s += v[i];
    }
    s = block_sum256(s, sm);
    const float inv = 1.f / s;
#pragma unroll
    for (int i = 0; i < 8; ++i) v[i] *= inv;
    *(uint4*)(XP + base) = pack8(v);
}

// ---------------------------------------------------------------------------
// Row mean of squares of Z (B,E) bf16: x2[row] = mean(Z[row,:]^2)
// ---------------------------------------------------------------------------
__global__ __launch_bounds__(256) void rowmeansq_bf_kernel(
    const u16* __restrict__ Z, float* __restrict__ out) {
    __shared__ float sm[4];
    const float v = bf2f(Z[(size_t)blockIdx.x * E + threadIdx.x]);
    const float s = block_sum256(v * v, sm);
    if (threadIdx.x == 0) out[blockIdx.x] = s * (1.0f / (float)E);
}

// ---------------------------------------------------------------------------
// Decode: xq = exp(t - x2[row]); XQ = xq / (P_NULL + rowsum(xq))  (bf16)
// ---------------------------------------------------------------------------
__global__ __launch_bounds__(256) void decode_bf_kernel(
    const u16* __restrict__ T, const float* __restrict__ x2z,
    u16* __restrict__ XQ) {
    __shared__ float sm[4];
    const size_t base = (size_t)blockIdx.x * K + (size_t)threadIdx.x * 8;
    const float x2 = x2z[blockIdx.x];
    float v[8];
    unpack8(*(const uint4*)(T + base), v);
    float s = 0.f;
#pragma unroll
    for (int i = 0; i < 8; ++i) {
        v[i] = __expf(v[i] - x2);
        s += v[i];
    }
    s = block_sum256(s, sm);
    const float scale = 1.f / (P_NULL + s);
#pragma unroll
    for (int i = 0; i < 8; ++i) v[i] *= scale;
    *(uint4*)(XQ + base) = pack8(v);
}

// ---------------------------------------------------------------------------
extern "C" void kernel_launch(void* const* d_in, const int* in_sizes, int n_in,
                              void* d_out, int out_size, void* d_ws, size_t ws_size,
                              hipStream_t stream) {
    const float* images = (const float*)d_in[0];  // (B,G)
    const float* xa     = (const float*)d_in[1];  // (G,K)
    const float* xb     = (const float*)d_in[2];  // (E,K)
    float* out = (float*)d_out;                   // (B,)

    // workspace carve-up (u16 elements, all regions 16B-aligned)
    u16* img_bf = (u16*)d_ws;                      // B*G   = 8M
    u16* xa_bf  = img_bf + (size_t)B * G;          // G*K   = 2M
    u16* xaT_bf = xa_bf + (size_t)G * K;           // K*G   = 2M
    u16* xb_bf  = xaT_bf + (size_t)K * G;          // E*K   = 512K
    u16* xbT_bf = xb_bf + (size_t)E * K;           // K*E   = 512K
    u16* pik_bf = xbT_bf + (size_t)K * E;          // B*K   = 16M
    u16* t_bf   = pik_bf + (size_t)B * K;          // B*K   = 16M
    u16* xp_bf  = t_bf + (size_t)B * K;            // B*K   = 16M
    u16* z_bf   = xp_bf + (size_t)B * K;           // B*E   = 2M
    float* x2z  = (float*)(z_bf + (size_t)B * E);  // B
    float* c2a  = x2z + B;                         // K
    float* c2b  = c2a + K;                         // K

    (void)hipMemsetAsync(d_out, 0, (size_t)B * sizeof(float), stream);
    (void)hipMemsetAsync(c2a, 0, (size_t)2 * K * sizeof(float), stream);

    // bf16 conversions + transposes
    f2bf_kernel<<<(B * G) / 2048, 256, 0, stream>>>(images, img_bf, B * G);
    f2bf_kernel<<<(G * K) / 2048, 256, 0, stream>>>(xa, xa_bf, G * K);
    f2bf_kernel<<<(E * K) / 2048, 256, 0, stream>>>(xb, xb_bf, E * K);
    transpose_bf_kernel<<<dim3(K / 32, G / 32), 256, 0, stream>>>(xa, xaT_bf, G, K);
    transpose_bf_kernel<<<dim3(K / 32, E / 32), 256, 0, stream>>>(xb, xbT_bf, E, K);

    // c2a[k] = mean_g xa[g,k]^2 ; c2b[k] = mean_e xb[e,k]^2
    colsq_kernel<<<dim3(K / 256, G / 128), 256, 0, stream>>>(xa, G, K, 1.0f / G, c2a);
    colsq_kernel<<<dim3(K / 256, E / 128), 256, 0, stream>>>(xb, E, K, 1.0f / E, c2b);

    // encode: t = images@xa * (2/G) - c2a   (per-row x2 cancels in softmax)
    mfma_gemm_kernel<EPI_BIAS_BF16><<<dim3(K / 128, B / 128), 256, 0, stream>>>(
        img_bf, xaT_bf, t_bf, c2a, nullptr, B, K, G, 2.0f / (float)G);
    softmax_bf_kernel<<<B, 256, 0, stream>>>(t_bf, pik_bf);

    // z = pik @ xb^T
    mfma_gemm_kernel<EPI_BF16><<<dim3(E / 128, B / 128), 256, 0, stream>>>(
        pik_bf, xb_bf, z_bf, nullptr, nullptr, B, E, K, 1.0f);

    for (int s = 0; s < N_STEP; ++s) {
        // t = z@xb * (2/E) - c2b
        mfma_gemm_kernel<EPI_BIAS_BF16><<<dim3(K / 128, B / 128), 256, 0, stream>>>(
            z_bf, xbT_bf, t_bf, c2b, nullptr, B, K, E, 2.0f / (float)E);
        // xp = pik*exp(t - max) / sum
        reweight_bf_kernel<<<B, 256, 0, stream>>>(t_bf, pik_bf, xp_bf);
        // z = xp @ xb^T
        mfma_gemm_kernel<EPI_BF16><<<dim3(E / 128, B / 128), 256, 0, stream>>>(
            xp_bf, xb_bf, z_bf, nullptr, nullptr, B, E, K, 1.0f);
    }

    // decode
    rowmeansq_bf_kernel<<<B, 256, 0, stream>>>(z_bf, x2z);
    mfma_gemm_kernel<EPI_BIAS_BF16><<<dim3(K / 128, B / 128), 256, 0, stream>>>(
        z_bf, xbT_bf, t_bf, c2b, nullptr, B, K, E, 2.0f / (float)E);
    decode_bf_kernel<<<B, 256, 0, stream>>>(t_bf, x2z, xp_bf);

    // recon = xq @ xa^T ; loss[b] = mean_g (recon - images)^2
    mfma_gemm_kernel<EPI_LOSS><<<dim3(G / 128, B / 128), 256, 0, stream>>>(
        xp_bf, xa_bf, out, nullptr, images, B, G, K, 1.0f);
}